// Round 7
// baseline (264.373 us; speedup 1.0000x reference)
//
#include <hip/hip_runtime.h>
#include <stdint.h>

// Problem constants
#define B_    16
#define C_    80
#define H_    128
#define W_    128
#define HW_   16384        // H_*W_
#define NBINS 1024
#define BIN_BASE 0x3C00u   // float bits>>16 lower bound for scores > ~0.0078
#define SORTN 1024
#define CNT_STRIDE 64      // pad per-batch tickets to 256B (64 u32) apart
#define F0_BITS 0x3F7F0000u  // 0.99609375f — eager pre-filter (top 1024-bin)
#define CHCAP 128u         // per-channel candidate cap (E[count]≈63; Poisson tail
                           // P(>128) ~1e-13; overflow -> exact fallback). MUST be 128
                           // (code uses >>7 / &127 for segment addressing).
#define PADTOT (C_ * (int)CHCAP)   // 10240 padded slots per batch

// ws layout (bytes):
//   ticket : B_*CNT_STRIDE*4 = 4096 @ 0      (zeroed each launch)
//   chCnt  : B_*C_*4 = 5120        @ 4096    (written unconditionally — no zeroing)
//   buf    : B_*C_*CHCAP*8 = 1.31MB @ 9216   (per-channel segments)
#define WS_TK_OFF  0
#define WS_CC_OFF  4096
#define WS_BUF_OFF 9216
#define WS_ZERO_BYTES 4096

// Horizontal 3-max (incl. center) of a 4-wide strip, halo via wave shuffle.
__device__ __forceinline__ float4 hmax3(float4 v, int srcL, int srcR, int tx) {
    float lft = __shfl(v.w, srcL);
    float rgt = __shfl(v.x, srcR);
    if (tx == 0)  lft = -1.f;
    if (tx == 31) rgt = -1.f;
    float4 h;
    h.x = fmaxf(v.x, fmaxf(lft, v.y));
    h.y = fmaxf(v.y, fmaxf(v.x, v.z));
    h.z = fmaxf(v.z, fmaxf(v.y, v.w));
    h.w = fmaxf(v.w, fmaxf(v.z, rgt));
    return h;
}

// Wave-aggregated LDS histogram add: if all valid lanes in the wave share one
// bin (the degenerate near-1.0 case), one atomic per wave instead of 64.
__device__ __forceinline__ void hist_add(unsigned* lh, bool valid, unsigned bin,
                                         int lane) {
    unsigned long long vm = __ballot(valid);
    if (vm == 0ull) return;
    int leader = __ffsll((unsigned long long)vm) - 1;
    unsigned lbin = __shfl(bin, leader);
    unsigned long long sm = __ballot(valid && bin == lbin);
    if (sm == vm) {
        if (lane == leader) atomicAdd(&lh[lbin], (unsigned)__popcll(vm));
    } else if (valid) {
        atomicAdd(&lh[bin], 1u);
    }
}

__device__ __forceinline__ unsigned long long make_key(unsigned bits, int c,
                                                       int y, int x) {
    unsigned idx = ((unsigned)c << 14) | ((unsigned)y << 7) | (unsigned)x;
    return ((unsigned long long)bits << 32) |
           (unsigned long long)(0xFFFFFFFFu - idx);
}

// Rolling 3-row NMS scan of one 128x128 channel by a 256-thread block.
// emit(f, m3x3, y, x) is invoked for ALL 16x4 pixels of each thread
// (unconditionally — safe for wave-ballot inside emit).
template <typename EmitFn>
__device__ __forceinline__ void nms_scan_channel(const float4* __restrict__ img,
                                                 EmitFn emit) {
    int tx = threadIdx.x & 31;   // col group (4 px)
    int ty = threadIdx.x >> 5;   // row strip (16 rows)
    int y0 = ty << 4;
    int lane = threadIdx.x & 63;
    int srcL = (lane > 0) ? lane - 1 : 0;
    int srcR = (lane < 63) ? lane + 1 : 63;
    const float4 neg1 = make_float4(-1.f, -1.f, -1.f, -1.f);

    float4 r0 = (y0 > 0) ? img[(y0 - 1) * 32 + tx] : neg1;
    float4 hprev = hmax3(r0, srcL, srcR, tx);
    float4 vcur = img[y0 * 32 + tx];
    float4 hcur = hmax3(vcur, srcL, srcR, tx);

    #pragma unroll 4
    for (int i = 0; i < 16; i++) {
        int y = y0 + i;
        float4 vn = (y + 1 < H_) ? img[(y + 1) * 32 + tx] : neg1;
        float4 hnext = hmax3(vn, srcL, srcR, tx);
        float mm[4];
        mm[0] = fmaxf(hprev.x, fmaxf(hcur.x, hnext.x));
        mm[1] = fmaxf(hprev.y, fmaxf(hcur.y, hnext.y));
        mm[2] = fmaxf(hprev.z, fmaxf(hcur.z, hnext.z));
        mm[3] = fmaxf(hprev.w, fmaxf(hcur.w, hnext.w));
        float vv[4] = {vcur.x, vcur.y, vcur.z, vcur.w};
        #pragma unroll
        for (int j = 0; j < 4; j++) emit(vv[j], mm[j], y, tx * 4 + j);
        hprev = hcur; hcur = hnext; vcur = vn;
    }
}

// 1024-bin suffix threshold: T = smallest bin with suffix-count >= 100 (0 if
// total < 100); cntHi = count strictly above T. All 256 threads participate.
__device__ __forceinline__ void find_suffix_thresh(const unsigned* __restrict__ h,
                                                   unsigned* __restrict__ seg,
                                                   unsigned* Tout,
                                                   unsigned* cntHiOut) {
    __syncthreads();   // make prior hist atomics visible
    int t = threadIdx.x;
    int base = t * 4;
    unsigned h0 = h[base], h1 = h[base + 1], h2 = h[base + 2], h3 = h[base + 3];
    seg[t] = h0 + h1 + h2 + h3;
    __syncthreads();
    for (int d = 1; d < 256; d <<= 1) {
        unsigned add = (t + d < 256) ? seg[t + d] : 0u;
        __syncthreads();
        seg[t] += add;
        __syncthreads();
    }
    unsigned mySuf = seg[t];
    unsigned nextSuf = (t < 255) ? seg[t + 1] : 0u;
    if (t == 0 && mySuf < 100u) { *Tout = 0u; *cntHiOut = mySuf - h0; }
    if (mySuf >= 100u && nextSuf < 100u) {
        unsigned cum = nextSuf;
        unsigned hv[4] = {h0, h1, h2, h3};
        for (int i = 3; i >= 0; i--) {
            cum += hv[i];
            if (cum >= 100u) { *Tout = (unsigned)(base + i); *cntHiOut = cum - hv[i]; break; }
        }
    }
    __syncthreads();
}

// ---------------------------------------------------------------------------
// Fused kernel. grid: B_*C_ = 1280 blocks of 256, one block per (b,c) channel.
// Stage 1 (all blocks): rolling-NMS scan own channel, candidates >= F0 to the
//   per-channel segment buf[bc*CHCAP], raw count to chCnt[bc] (no atomics on
//   shared counters, no pre-zeroing needed).
// Stage 2 (the block drawing the last per-batch ticket): refine the batch's
//   <=80*128 padded candidate slots (hist -> T1, sub-hist -> U, compact),
//   adaptive bitonic sort, decode, write. Fallback (overflow / <100 cands):
//   exact in-block 3-pass re-scan of the batch's 80 channels.
// ---------------------------------------------------------------------------
__global__ __launch_bounds__(256) void nms_topk(const float* __restrict__ hm,
                                                const float* __restrict__ offset,
                                                const float* __restrict__ wh,
                                                unsigned* __restrict__ ticket,
                                                unsigned* __restrict__ chCnt,
                                                unsigned long long* __restrict__ buf,
                                                float* __restrict__ out) {
    __shared__ unsigned long long s[SORTN];   // stage1: candidate list; stage2: sort
    __shared__ unsigned lh[NBINS];
    __shared__ unsigned seg[256];
    __shared__ unsigned shC[256];
    __shared__ unsigned sufC[256];
    __shared__ unsigned scnt[C_];
    __shared__ unsigned lcnt, tkS, rawTotS, ovfS, T1s, cntHiS, Us, cntL;

    int t = threadIdx.x;
    int lane = t & 63;
    int bc = blockIdx.x;
    int b  = bc / C_;
    int c  = bc - b * C_;
    if (t == 0) lcnt = 0u;
    __syncthreads();

    // ---- stage 1: scan own channel
    const float4* img = (const float4*)(hm + (size_t)bc * HW_);
    nms_scan_channel(img, [&](float f, float m, int y, int x) {
        if (f >= m && __float_as_uint(f) >= F0_BITS) {
            unsigned pos = atomicAdd(&lcnt, 1u);
            if (pos < CHCAP) s[pos] = make_key(__float_as_uint(f), c, y, x);
        }
    });
    __syncthreads();
    unsigned raw = lcnt;
    unsigned cw  = raw > CHCAP ? CHCAP : raw;
    unsigned long long* myseg = buf + (size_t)bc * CHCAP;
    for (unsigned i = t; i < cw; i += 256) myseg[i] = s[i];
    if (t == 0) chCnt[bc] = raw;
    __threadfence();                       // release: flush stores device-wide
    __syncthreads();
    if (t == 0) tkS = atomicAdd(&ticket[b * CNT_STRIDE], 1u);
    __syncthreads();
    if (tkS != (unsigned)(C_ - 1)) return; // not the last block of this batch

    // ---- stage 2: decoder for batch b
    __threadfence();                       // acquire: invalidate caches

    for (int i = t; i < NBINS; i += 256) lh[i] = 0u;
    shC[t] = 0u;
    if (t == 0) { rawTotS = 0u; ovfS = 0u; cntL = 0u; T1s = 0u; cntHiS = 0u; Us = 0u; }
    __syncthreads();
    if (t < C_) {
        unsigned r = chCnt[b * C_ + t];
        atomicAdd(&rawTotS, r);
        if (r > CHCAP) atomicOr(&ovfS, 1u);
        scnt[t] = r > CHCAP ? CHCAP : r;
    }
    __syncthreads();
    unsigned rawTot = rawTotS;
    bool fb = (rawTot < 100u) || (ovfS != 0u);

    const unsigned long long* bufb = buf + (size_t)b * C_ * CHCAP;
    unsigned n2;
    if (!fb) {
        // phase A: 1024-bin hist of bits>>16 over padded slots, wave-aggregated
        for (unsigned i0 = 0; i0 < (unsigned)PADTOT; i0 += 256) {
            unsigned i  = i0 + t;
            unsigned sg = i >> 7;              // CHCAP == 128
            unsigned off = i & (CHCAP - 1u);
            bool valid = off < scnt[sg];
            unsigned bin = 0u;
            if (valid) {
                unsigned bits = (unsigned)(bufb[i] >> 32);
                bin = (bits >> 16) - BIN_BASE;
                if (bin > NBINS - 1) bin = NBINS - 1;
            }
            hist_add(lh, valid, bin, lane);
        }
        find_suffix_thresh(lh, seg, &T1s, &cntHiS);
        unsigned T1 = T1s, cntHi = cntHiS;

        // phase C: 256-sub-bin hist of bits[15:8] within bin T1 -> U
        for (unsigned i0 = 0; i0 < (unsigned)PADTOT; i0 += 256) {
            unsigned i = i0 + t;
            unsigned sg = i >> 7, off = i & (CHCAP - 1u);
            if (off < scnt[sg]) {
                unsigned bits = (unsigned)(bufb[i] >> 32);
                unsigned bin = (bits >> 16) - BIN_BASE;
                if (bin > NBINS - 1) bin = NBINS - 1;
                if (bin == T1) atomicAdd(&shC[(bits >> 8) & 255u], 1u);
            }
        }
        __syncthreads();
        sufC[t] = shC[t];
        __syncthreads();
        for (int d = 1; d < 256; d <<= 1) {
            unsigned add = (t + d < 256) ? sufC[t + d] : 0u;
            __syncthreads();
            sufC[t] += add;
            __syncthreads();
        }
        unsigned myS = cntHi + sufC[t];
        unsigned nxS = cntHi + ((t < 255) ? sufC[t + 1] : 0u);
        if (t == 0 && myS < 100u) Us = 0u;
        if (myS >= 100u && nxS < 100u) Us = (unsigned)t;
        __syncthreads();
        unsigned U = Us;

        // phase D: wave-aggregated compaction into s
        for (unsigned i0 = 0; i0 < (unsigned)PADTOT; i0 += 256) {
            unsigned i = i0 + t;
            unsigned sg = i >> 7, off = i & (CHCAP - 1u);
            bool valid = off < scnt[sg];
            unsigned long long key = 0ull;
            bool take = false;
            if (valid) {
                key = bufb[i];
                unsigned bits = (unsigned)(key >> 32);
                unsigned bin = (bits >> 16) - BIN_BASE;
                if (bin > NBINS - 1) bin = NBINS - 1;
                take = (bin > T1) || (bin == T1 && ((bits >> 8) & 255u) >= U);
            }
            unsigned long long m = __ballot(take);
            if (m != 0ull) {
                int leader = __ffsll((unsigned long long)m) - 1;
                unsigned wcnt = (unsigned)__popcll(m);
                unsigned wbase = 0u;
                if (lane == leader) wbase = atomicAdd(&cntL, wcnt);
                wbase = __shfl(wbase, leader);
                if (take) {
                    unsigned prefix = (unsigned)__popcll(m & ((1ull << lane) - 1ull));
                    unsigned pos = wbase + prefix;
                    if (pos < SORTN) s[pos] = key;
                }
            }
        }
        __syncthreads();
        n2 = cntL;
    } else {
        // ---- fallback: in-block exact re-scan of this batch's 80 channels
        // pass 1: 1024-bin hist over all local maxima with f > 0.01
        for (int cc = 0; cc < C_; cc++) {
            const float4* im = (const float4*)(hm + ((size_t)b * C_ + cc) * HW_);
            nms_scan_channel(im, [&](float f, float m, int y, int x) {
                bool hit = (f > 0.01f && f >= m);
                unsigned bin = 0u;
                if (hit) {
                    bin = (__float_as_uint(f) >> 16) - BIN_BASE;
                    if (bin > NBINS - 1) bin = NBINS - 1;
                }
                hist_add(lh, hit, bin, lane);
            });
        }
        find_suffix_thresh(lh, seg, &T1s, &cntHiS);
        unsigned T1 = T1s, cntHi = cntHiS;

        // pass 2: collect bin>T1 keys; sub-hist bits[15:8] for bin==T1
        for (int cc = 0; cc < C_; cc++) {
            const float4* im = (const float4*)(hm + ((size_t)b * C_ + cc) * HW_);
            nms_scan_channel(im, [&](float f, float m, int y, int x) {
                if (f > 0.01f && f >= m) {
                    unsigned bits = __float_as_uint(f);
                    unsigned bin = (bits >> 16) - BIN_BASE;
                    if (bin > NBINS - 1) bin = NBINS - 1;
                    if (bin > T1) {
                        unsigned pos = atomicAdd(&cntL, 1u);
                        if (pos < SORTN) s[pos] = make_key(bits, cc, y, x);
                    } else if (bin == T1) {
                        atomicAdd(&shC[(bits >> 8) & 255u], 1u);
                    }
                }
            });
        }
        __syncthreads();
        sufC[t] = shC[t];
        __syncthreads();
        for (int d = 1; d < 256; d <<= 1) {
            unsigned add = (t + d < 256) ? sufC[t + d] : 0u;
            __syncthreads();
            sufC[t] += add;
            __syncthreads();
        }
        unsigned myS = cntHi + sufC[t];
        unsigned nxS = cntHi + ((t < 255) ? sufC[t + 1] : 0u);
        if (t == 0 && myS < 100u) Us = 0u;
        if (myS >= 100u && nxS < 100u) Us = (unsigned)t;
        __syncthreads();
        unsigned U = Us;

        // pass 3: collect bin==T1 && sub>=U keys
        for (int cc = 0; cc < C_; cc++) {
            const float4* im = (const float4*)(hm + ((size_t)b * C_ + cc) * HW_);
            nms_scan_channel(im, [&](float f, float m, int y, int x) {
                if (f > 0.01f && f >= m) {
                    unsigned bits = __float_as_uint(f);
                    unsigned bin = (bits >> 16) - BIN_BASE;
                    if (bin > NBINS - 1) bin = NBINS - 1;
                    if (bin == T1 && ((bits >> 8) & 255u) >= U) {
                        unsigned pos = atomicAdd(&cntL, 1u);
                        if (pos < SORTN) s[pos] = make_key(bits, cc, y, x);
                    }
                }
            });
        }
        __syncthreads();
        n2 = cntL;
    }
    if (n2 > SORTN) n2 = SORTN;

    // adaptive bitonic sort descending (0 pads sink to the bottom)
    unsigned SN = (n2 <= 256u) ? 256u : SORTN;
    for (unsigned i = n2 + t; i < SN; i += 256) s[i] = 0ull;
    __syncthreads();
    for (unsigned k = 2; k <= SN; k <<= 1) {
        for (unsigned j = k >> 1; j > 0; j >>= 1) {
            for (unsigned tt = t; tt < SN; tt += 256) {
                unsigned ixj = tt ^ j;
                if (ixj > tt) {
                    unsigned long long a = s[tt], bb = s[ixj];
                    bool desc = ((tt & k) == 0u);
                    if (desc ? (a < bb) : (a > bb)) { s[tt] = bb; s[ixj] = a; }
                }
            }
            __syncthreads();
        }
    }

    // decode + write
    int r = t;
    if (r < 100) {
        float idv, sc, b0, b1, b2, b3;
        if ((unsigned)r < n2) {
            unsigned long long key = s[r];
            unsigned bits = (unsigned)(key >> 32);
            unsigned idx  = 0xFFFFFFFFu - (unsigned)(key & 0xFFFFFFFFu);
            float v = __uint_as_float(bits);
            int cc = (int)(idx >> 14);
            int sp = (int)(idx & 16383u);
            int y  = sp >> 7;
            int x  = sp & 127;
            const float* offb = offset + (size_t)b * 2 * HW_;
            const float* whb  = wh + (size_t)b * 2 * HW_;
            float ox = offb[sp], oy = offb[HW_ + sp];
            float wwv = whb[sp], hh = whb[HW_ + sp];
            float cx = (float)x + ox;
            float cy = (float)y + oy;
            idv = (float)cc;
            sc  = v;
            b0 = (cx - wwv * 0.5f) * 4.0f;
            b1 = (cy - hh * 0.5f) * 4.0f;
            b2 = (cx + wwv * 0.5f) * 4.0f;
            b3 = (cy + hh * 0.5f) * 4.0f;
        } else {
            idv = -1.0f; sc = -1.0f;
            b0 = b1 = b2 = b3 = -4.0f;   // where(keep, bbox, -1) * SCALE
        }
        int o = b * 100 + r;
        out[o]        = idv;
        out[1600 + o] = sc;
        float* bb = out + 3200 + o * 4;
        bb[0] = b0; bb[1] = b1; bb[2] = b2; bb[3] = b3;
    }
}

// ---------------------------------------------------------------------------
extern "C" void kernel_launch(void* const* d_in, const int* in_sizes, int n_in,
                              void* d_out, int out_size, void* d_ws, size_t ws_size,
                              hipStream_t stream) {
    const float* heatmap = (const float*)d_in[0];
    const float* offset  = (const float*)d_in[1];
    const float* wh      = (const float*)d_in[2];
    float* out = (float*)d_out;

    char* ws = (char*)d_ws;
    unsigned* ticket = (unsigned*)(ws + WS_TK_OFF);
    unsigned* chCnt  = (unsigned*)(ws + WS_CC_OFF);
    unsigned long long* buf = (unsigned long long*)(ws + WS_BUF_OFF);

    hipMemsetAsync(d_ws, 0, WS_ZERO_BYTES, stream);
    nms_topk<<<dim3(B_ * C_), dim3(256), 0, stream>>>(heatmap, offset, wh,
                                                      ticket, chCnt, buf, out);
}

// Round 8
// 163.060 us; speedup vs baseline: 1.6213x; 1.6213x over previous
//
#include <hip/hip_runtime.h>
#include <stdint.h>

// Problem constants
#define B_    16
#define C_    80
#define H_    128
#define W_    128
#define HW_   16384        // H_*W_
#define NBINS 1024
#define BIN_BASE 0x3C00u   // float bits>>16 lower bound for scores > ~0.0078
#define SORTN 1024
#define F0_BITS 0x3F7F0000u  // 0.99609375f — eager pre-filter (top 1024-bin)
#define CHCAP 128u         // per-channel candidate cap (E[count]≈63; overflow ->
                           // exact fallback). MUST be 128 (code uses >>7 / &127).
#define PADTOT (C_ * (int)CHCAP)   // 10240 padded slots per batch

// ws layout (bytes) — NO zeroed state; everything written unconditionally:
//   chCnt : B_*C_*4 = 5120  @ 0
//   buf   : B_*C_*CHCAP*8 = 1.31MB @ 8192
#define WS_CC_OFF  0
#define WS_BUF_OFF 8192

// Horizontal 3-max (incl. center) of a 4-wide strip, halo via wave shuffle.
__device__ __forceinline__ float4 hmax3(float4 v, int srcL, int srcR, int tx) {
    float lft = __shfl(v.w, srcL);
    float rgt = __shfl(v.x, srcR);
    if (tx == 0)  lft = -1.f;
    if (tx == 31) rgt = -1.f;
    float4 h;
    h.x = fmaxf(v.x, fmaxf(lft, v.y));
    h.y = fmaxf(v.y, fmaxf(v.x, v.z));
    h.z = fmaxf(v.z, fmaxf(v.y, v.w));
    h.w = fmaxf(v.w, fmaxf(v.z, rgt));
    return h;
}

// Wave-aggregated LDS histogram add (degenerate same-bin case -> 1 atomic/wave).
__device__ __forceinline__ void hist_add(unsigned* lh, bool valid, unsigned bin,
                                         int lane) {
    unsigned long long vm = __ballot(valid);
    if (vm == 0ull) return;
    int leader = __ffsll((unsigned long long)vm) - 1;
    unsigned lbin = __shfl(bin, leader);
    unsigned long long sm = __ballot(valid && bin == lbin);
    if (sm == vm) {
        if (lane == leader) atomicAdd(&lh[lbin], (unsigned)__popcll(vm));
    } else if (valid) {
        atomicAdd(&lh[bin], 1u);
    }
}

__device__ __forceinline__ unsigned long long make_key(unsigned bits, int c,
                                                       int y, int x) {
    unsigned idx = ((unsigned)c << 14) | ((unsigned)y << 7) | (unsigned)x;
    return ((unsigned long long)bits << 32) |
           (unsigned long long)(0xFFFFFFFFu - idx);
}

// Rolling 3-row NMS scan of one 128x128 channel by a 256-thread block.
// emit(f, m3x3, y, x) invoked for ALL pixels (safe for wave-ballot inside).
template <typename EmitFn>
__device__ __forceinline__ void nms_scan_channel(const float4* __restrict__ img,
                                                 EmitFn emit) {
    int tx = threadIdx.x & 31;   // col group (4 px)
    int ty = threadIdx.x >> 5;   // row strip (16 rows)
    int y0 = ty << 4;
    int lane = threadIdx.x & 63;
    int srcL = (lane > 0) ? lane - 1 : 0;
    int srcR = (lane < 63) ? lane + 1 : 63;
    const float4 neg1 = make_float4(-1.f, -1.f, -1.f, -1.f);

    float4 r0 = (y0 > 0) ? img[(y0 - 1) * 32 + tx] : neg1;
    float4 hprev = hmax3(r0, srcL, srcR, tx);
    float4 vcur = img[y0 * 32 + tx];
    float4 hcur = hmax3(vcur, srcL, srcR, tx);

    #pragma unroll 4
    for (int i = 0; i < 16; i++) {
        int y = y0 + i;
        float4 vn = (y + 1 < H_) ? img[(y + 1) * 32 + tx] : neg1;
        float4 hnext = hmax3(vn, srcL, srcR, tx);
        float mm[4];
        mm[0] = fmaxf(hprev.x, fmaxf(hcur.x, hnext.x));
        mm[1] = fmaxf(hprev.y, fmaxf(hcur.y, hnext.y));
        mm[2] = fmaxf(hprev.z, fmaxf(hcur.z, hnext.z));
        mm[3] = fmaxf(hprev.w, fmaxf(hcur.w, hnext.w));
        float vv[4] = {vcur.x, vcur.y, vcur.z, vcur.w};
        #pragma unroll
        for (int j = 0; j < 4; j++) emit(vv[j], mm[j], y, tx * 4 + j);
        hprev = hcur; hcur = hnext; vcur = vn;
    }
}

// 1024-bin suffix threshold (fallback path): T = smallest bin with suffix >=
// 100 (0 if total < 100); cntHi = count strictly above T.
__device__ __forceinline__ void find_suffix_thresh(const unsigned* __restrict__ h,
                                                   unsigned* __restrict__ seg,
                                                   unsigned* Tout,
                                                   unsigned* cntHiOut) {
    __syncthreads();
    int t = threadIdx.x;
    int base = t * 4;
    unsigned h0 = h[base], h1 = h[base + 1], h2 = h[base + 2], h3 = h[base + 3];
    seg[t] = h0 + h1 + h2 + h3;
    __syncthreads();
    for (int d = 1; d < 256; d <<= 1) {
        unsigned add = (t + d < 256) ? seg[t + d] : 0u;
        __syncthreads();
        seg[t] += add;
        __syncthreads();
    }
    unsigned mySuf = seg[t];
    unsigned nextSuf = (t < 255) ? seg[t + 1] : 0u;
    if (t == 0 && mySuf < 100u) { *Tout = 0u; *cntHiOut = mySuf - h0; }
    if (mySuf >= 100u && nextSuf < 100u) {
        unsigned cum = nextSuf;
        unsigned hv[4] = {h0, h1, h2, h3};
        for (int i = 3; i >= 0; i--) {
            cum += hv[i];
            if (cum >= 100u) { *Tout = (unsigned)(base + i); *cntHiOut = cum - hv[i]; break; }
        }
    }
    __syncthreads();
}

// ---------------------------------------------------------------------------
// K1: eager NMS scan. One block per (b,c) channel. Candidates (local max AND
// bits >= F0) -> LDS list -> per-channel segment buf[bc*CHCAP]; raw count to
// chCnt[bc] unconditionally (no global atomics, no pre-zeroed state).
// grid: B_*C_ = 1280 blocks of 256.
// ---------------------------------------------------------------------------
__global__ __launch_bounds__(256) void nms_eager(const float* __restrict__ hm,
                                                 unsigned* __restrict__ chCnt,
                                                 unsigned long long* __restrict__ buf) {
    __shared__ unsigned long long s[CHCAP];
    __shared__ unsigned lcnt;
    if (threadIdx.x == 0) lcnt = 0u;
    __syncthreads();

    int bc = blockIdx.x;         // b*C_ + c
    int c  = bc % C_;
    const float4* img = (const float4*)(hm + (size_t)bc * HW_);

    nms_scan_channel(img, [&](float f, float m, int y, int x) {
        if (f >= m && __float_as_uint(f) >= F0_BITS) {
            unsigned pos = atomicAdd(&lcnt, 1u);
            if (pos < CHCAP) s[pos] = make_key(__float_as_uint(f), c, y, x);
        }
    });
    __syncthreads();

    unsigned raw = lcnt;
    unsigned cw  = raw > CHCAP ? CHCAP : raw;
    unsigned long long* myseg = buf + (size_t)bc * CHCAP;
    for (unsigned i = threadIdx.x; i < cw; i += 256) myseg[i] = s[i];
    if (threadIdx.x == 0) chCnt[bc] = raw;
}

// ---------------------------------------------------------------------------
// K2: per-batch top-100. Fast path (2 passes): all eager keys have bits >= F0,
// so a single 512-bin hist of (bits-F0)>>8 + suffix scan gives the cut U2 and
// exact take-count; then one wave-aggregated compact pass. Guards (overflowed
// channel / <100 total / take-count > SORTN) -> exact in-block 3-pass re-scan.
// Adaptive bitonic sort desc + decode + write. grid: B_ blocks of 256.
// ---------------------------------------------------------------------------
__global__ __launch_bounds__(256) void topk_decode(const float* __restrict__ hm,
                                                   const unsigned long long* __restrict__ buf,
                                                   const unsigned* __restrict__ chCnt,
                                                   const float* __restrict__ offset,
                                                   const float* __restrict__ wh,
                                                   float* __restrict__ out) {
    int b = blockIdx.x;
    int t = threadIdx.x;
    int lane = t & 63;
    __shared__ unsigned long long s[SORTN];
    __shared__ unsigned lh[NBINS];    // fast path uses [0..511]; fb uses all
    __shared__ unsigned seg[256];
    __shared__ unsigned shC[256];
    __shared__ unsigned sufC[256];
    __shared__ unsigned scnt[C_];
    __shared__ unsigned rawTotS, ovfS, U2s, takeS, T1s, cntHiS, Us, cntL;

    if (t == 0) { rawTotS = 0u; ovfS = 0u; cntL = 0u; U2s = 0u; takeS = 0u;
                  T1s = 0u; cntHiS = 0u; Us = 0u; }
    for (int i = t; i < NBINS; i += 256) lh[i] = 0u;
    shC[t] = 0u;
    __syncthreads();
    if (t < C_) {
        unsigned r = chCnt[b * C_ + t];
        atomicAdd(&rawTotS, r);
        if (r > CHCAP) atomicOr(&ovfS, 1u);
        scnt[t] = r > CHCAP ? CHCAP : r;
    }
    __syncthreads();
    bool fb = (rawTotS < 100u) || (ovfS != 0u);

    const unsigned long long* bufb = buf + (size_t)b * C_ * CHCAP;
    unsigned n2 = 0u;

    if (!fb) {
        // pass 1: 512-bin hist of (bits - F0) >> 8, clamped to 511
        #pragma unroll 4
        for (unsigned i0 = 0; i0 < (unsigned)PADTOT; i0 += 256) {
            unsigned i  = i0 + t;
            unsigned sg = i >> 7;              // CHCAP == 128
            unsigned off = i & (CHCAP - 1u);
            if (off < scnt[sg]) {
                unsigned bits = (unsigned)(bufb[i] >> 32);
                unsigned bin = (bits - F0_BITS) >> 8;
                if (bin > 511u) bin = 511u;
                atomicAdd(&lh[bin], 1u);
            }
        }
        __syncthreads();
        // suffix scan over 512 bins (2 per thread) -> U2, takeCnt
        unsigned g0 = lh[t * 2], g1 = lh[t * 2 + 1];
        seg[t] = g0 + g1;
        __syncthreads();
        for (int d = 1; d < 256; d <<= 1) {
            unsigned add = (t + d < 256) ? seg[t + d] : 0u;
            __syncthreads();
            seg[t] += add;
            __syncthreads();
        }
        unsigned mySuf = seg[t];
        unsigned nextSuf = (t < 255) ? seg[t + 1] : 0u;
        if (mySuf >= 100u && nextSuf < 100u) {   // exists since rawTot >= 100
            unsigned cum1 = nextSuf + g1;
            if (cum1 >= 100u) { U2s = (unsigned)(t * 2 + 1); takeS = cum1; }
            else              { U2s = (unsigned)(t * 2);     takeS = cum1 + g0; }
        }
        __syncthreads();
        unsigned U2 = U2s, takeCnt = takeS;
        if (takeCnt > SORTN) {
            fb = true;   // massive tie block — resolve exactly below
        } else {
            // pass 2: wave-aggregated compact of keys with bin >= U2
            #pragma unroll 4
            for (unsigned i0 = 0; i0 < (unsigned)PADTOT; i0 += 256) {
                unsigned i = i0 + t;
                unsigned sg = i >> 7, off = i & (CHCAP - 1u);
                bool valid = off < scnt[sg];
                unsigned long long key = 0ull;
                bool take = false;
                if (valid) {
                    key = bufb[i];
                    unsigned bits = (unsigned)(key >> 32);
                    unsigned bin = (bits - F0_BITS) >> 8;
                    if (bin > 511u) bin = 511u;
                    take = (bin >= U2);
                }
                unsigned long long m = __ballot(take);
                if (m != 0ull) {
                    int leader = __ffsll((unsigned long long)m) - 1;
                    unsigned wcnt = (unsigned)__popcll(m);
                    unsigned wbase = 0u;
                    if (lane == leader) wbase = atomicAdd(&cntL, wcnt);
                    wbase = __shfl(wbase, leader);
                    if (take) {
                        unsigned prefix = (unsigned)__popcll(m & ((1ull << lane) - 1ull));
                        s[wbase + prefix] = key;
                    }
                }
            }
            __syncthreads();
            n2 = cntL;
        }
    }

    if (fb) {
        // ---- exact fallback: in-block 3-pass re-scan of this batch's channels
        __syncthreads();
        for (int i = t; i < NBINS; i += 256) lh[i] = 0u;
        shC[t] = 0u;
        if (t == 0) { cntL = 0u; T1s = 0u; cntHiS = 0u; Us = 0u; }
        __syncthreads();

        // pass 1: 1024-bin hist over all local maxima with f > 0.01
        for (int cc = 0; cc < C_; cc++) {
            const float4* im = (const float4*)(hm + ((size_t)b * C_ + cc) * HW_);
            nms_scan_channel(im, [&](float f, float m, int y, int x) {
                bool hit = (f > 0.01f && f >= m);
                unsigned bin = 0u;
                if (hit) {
                    bin = (__float_as_uint(f) >> 16) - BIN_BASE;
                    if (bin > NBINS - 1) bin = NBINS - 1;
                }
                hist_add(lh, hit, bin, lane);
            });
        }
        find_suffix_thresh(lh, seg, &T1s, &cntHiS);
        unsigned T1 = T1s, cntHi = cntHiS;

        // pass 2: collect bin>T1 keys; sub-hist bits[15:8] for bin==T1
        for (int cc = 0; cc < C_; cc++) {
            const float4* im = (const float4*)(hm + ((size_t)b * C_ + cc) * HW_);
            nms_scan_channel(im, [&](float f, float m, int y, int x) {
                if (f > 0.01f && f >= m) {
                    unsigned bits = __float_as_uint(f);
                    unsigned bin = (bits >> 16) - BIN_BASE;
                    if (bin > NBINS - 1) bin = NBINS - 1;
                    if (bin > T1) {
                        unsigned pos = atomicAdd(&cntL, 1u);
                        if (pos < SORTN) s[pos] = make_key(bits, cc, y, x);
                    } else if (bin == T1) {
                        atomicAdd(&shC[(bits >> 8) & 255u], 1u);
                    }
                }
            });
        }
        __syncthreads();
        sufC[t] = shC[t];
        __syncthreads();
        for (int d = 1; d < 256; d <<= 1) {
            unsigned add = (t + d < 256) ? sufC[t + d] : 0u;
            __syncthreads();
            sufC[t] += add;
            __syncthreads();
        }
        unsigned myS = cntHi + sufC[t];
        unsigned nxS = cntHi + ((t < 255) ? sufC[t + 1] : 0u);
        if (t == 0 && myS < 100u) Us = 0u;
        if (myS >= 100u && nxS < 100u) Us = (unsigned)t;
        __syncthreads();
        unsigned U = Us;

        // pass 3: collect bin==T1 && sub>=U keys
        for (int cc = 0; cc < C_; cc++) {
            const float4* im = (const float4*)(hm + ((size_t)b * C_ + cc) * HW_);
            nms_scan_channel(im, [&](float f, float m, int y, int x) {
                if (f > 0.01f && f >= m) {
                    unsigned bits = __float_as_uint(f);
                    unsigned bin = (bits >> 16) - BIN_BASE;
                    if (bin > NBINS - 1) bin = NBINS - 1;
                    if (bin == T1 && ((bits >> 8) & 255u) >= U) {
                        unsigned pos = atomicAdd(&cntL, 1u);
                        if (pos < SORTN) s[pos] = make_key(bits, cc, y, x);
                    }
                }
            });
        }
        __syncthreads();
        n2 = cntL;
    }
    if (n2 > SORTN) n2 = SORTN;

    // adaptive bitonic sort descending (0 pads sink to the bottom)
    unsigned SN = (n2 <= 256u) ? 256u : SORTN;
    for (unsigned i = n2 + t; i < SN; i += 256) s[i] = 0ull;
    __syncthreads();
    for (unsigned k = 2; k <= SN; k <<= 1) {
        for (unsigned j = k >> 1; j > 0; j >>= 1) {
            for (unsigned tt = t; tt < SN; tt += 256) {
                unsigned ixj = tt ^ j;
                if (ixj > tt) {
                    unsigned long long a = s[tt], bb = s[ixj];
                    bool desc = ((tt & k) == 0u);
                    if (desc ? (a < bb) : (a > bb)) { s[tt] = bb; s[ixj] = a; }
                }
            }
            __syncthreads();
        }
    }

    // decode + write
    int r = t;
    if (r < 100) {
        float idv, sc, b0, b1, b2, b3;
        if ((unsigned)r < n2) {
            unsigned long long key = s[r];
            unsigned bits = (unsigned)(key >> 32);
            unsigned idx  = 0xFFFFFFFFu - (unsigned)(key & 0xFFFFFFFFu);
            float v = __uint_as_float(bits);
            int cc = (int)(idx >> 14);
            int sp = (int)(idx & 16383u);
            int y  = sp >> 7;
            int x  = sp & 127;
            const float* offb = offset + (size_t)b * 2 * HW_;
            const float* whb  = wh + (size_t)b * 2 * HW_;
            float ox = offb[sp], oy = offb[HW_ + sp];
            float wwv = whb[sp], hh = whb[HW_ + sp];
            float cx = (float)x + ox;
            float cy = (float)y + oy;
            idv = (float)cc;
            sc  = v;
            b0 = (cx - wwv * 0.5f) * 4.0f;
            b1 = (cy - hh * 0.5f) * 4.0f;
            b2 = (cx + wwv * 0.5f) * 4.0f;
            b3 = (cy + hh * 0.5f) * 4.0f;
        } else {
            idv = -1.0f; sc = -1.0f;
            b0 = b1 = b2 = b3 = -4.0f;   // where(keep, bbox, -1) * SCALE
        }
        int o = b * 100 + r;
        out[o]        = idv;
        out[1600 + o] = sc;
        float* bb = out + 3200 + o * 4;
        bb[0] = b0; bb[1] = b1; bb[2] = b2; bb[3] = b3;
    }
}

// ---------------------------------------------------------------------------
extern "C" void kernel_launch(void* const* d_in, const int* in_sizes, int n_in,
                              void* d_out, int out_size, void* d_ws, size_t ws_size,
                              hipStream_t stream) {
    const float* heatmap = (const float*)d_in[0];
    const float* offset  = (const float*)d_in[1];
    const float* wh      = (const float*)d_in[2];
    float* out = (float*)d_out;

    char* ws = (char*)d_ws;
    unsigned* chCnt = (unsigned*)(ws + WS_CC_OFF);
    unsigned long long* buf = (unsigned long long*)(ws + WS_BUF_OFF);

    nms_eager<<<dim3(B_ * C_), dim3(256), 0, stream>>>(heatmap, chCnt, buf);
    topk_decode<<<dim3(B_), dim3(256), 0, stream>>>(heatmap, buf, chCnt,
                                                    offset, wh, out);
}

// Round 9
// 148.102 us; speedup vs baseline: 1.7851x; 1.1010x over previous
//
#include <hip/hip_runtime.h>
#include <stdint.h>

// Problem constants
#define B_    16
#define C_    80
#define H_    128
#define W_    128
#define HW_   16384        // H_*W_
#define NBINS 1024
#define BIN_BASE 0x3C00u   // float bits>>16 lower bound for scores > ~0.0078
#define SORTN 1024
// Eager pre-filter: 0.9992675781f. Per-batch candidates ~960 (>=100 w/ 27-sigma
// margin on uniform data); per-channel ~12 (cap 64 untouchable). Any violation
// -> exact fallback.
#define F1_BITS 0x3F7FD000u
#define CHCAP 64u          // per-channel candidate cap. MUST be 64 (>>6 / &63).
#define PADTOT (C_ * (int)CHCAP)   // 5120 padded slots per batch
#define FSHIFT 5           // fine-hist shift: bin = (bits - F1_BITS) >> 5
#define FBINS 512          // logical 384 used ((0x3000>>5)=384); padded to 512
#define LSCAP 2048         // LDS stash cap (mean 960, 34-sigma margin)

// ws layout (bytes) — NO zeroed state; everything written unconditionally:
//   chCnt : B_*C_*4 = 5120  @ 0
//   buf   : B_*C_*CHCAP*8 = 640KB @ 8192
#define WS_CC_OFF  0
#define WS_BUF_OFF 8192

// Horizontal 3-max (incl. center) of a 4-wide strip, halo via wave shuffle.
__device__ __forceinline__ float4 hmax3(float4 v, int srcL, int srcR, int tx) {
    float lft = __shfl(v.w, srcL);
    float rgt = __shfl(v.x, srcR);
    if (tx == 0)  lft = -1.f;
    if (tx == 31) rgt = -1.f;
    float4 h;
    h.x = fmaxf(v.x, fmaxf(lft, v.y));
    h.y = fmaxf(v.y, fmaxf(v.x, v.z));
    h.z = fmaxf(v.z, fmaxf(v.y, v.w));
    h.w = fmaxf(v.w, fmaxf(v.z, rgt));
    return h;
}

// Wave-aggregated LDS histogram add (degenerate same-bin case -> 1 atomic/wave).
__device__ __forceinline__ void hist_add(unsigned* lh, bool valid, unsigned bin,
                                         int lane) {
    unsigned long long vm = __ballot(valid);
    if (vm == 0ull) return;
    int leader = __ffsll((unsigned long long)vm) - 1;
    unsigned lbin = __shfl(bin, leader);
    unsigned long long sm = __ballot(valid && bin == lbin);
    if (sm == vm) {
        if (lane == leader) atomicAdd(&lh[lbin], (unsigned)__popcll(vm));
    } else if (valid) {
        atomicAdd(&lh[bin], 1u);
    }
}

__device__ __forceinline__ unsigned long long make_key(unsigned bits, int c,
                                                       int y, int x) {
    unsigned idx = ((unsigned)c << 14) | ((unsigned)y << 7) | (unsigned)x;
    return ((unsigned long long)bits << 32) |
           (unsigned long long)(0xFFFFFFFFu - idx);
}

// Rolling 3-row NMS scan of one 128x128 channel (fallback path only).
// emit(f, m3x3, y, x) invoked for ALL pixels (safe for wave-ballot inside).
template <typename EmitFn>
__device__ __forceinline__ void nms_scan_channel(const float4* __restrict__ img,
                                                 EmitFn emit) {
    int tx = threadIdx.x & 31;
    int ty = threadIdx.x >> 5;
    int y0 = ty << 4;
    int lane = threadIdx.x & 63;
    int srcL = (lane > 0) ? lane - 1 : 0;
    int srcR = (lane < 63) ? lane + 1 : 63;
    const float4 neg1 = make_float4(-1.f, -1.f, -1.f, -1.f);

    float4 r0 = (y0 > 0) ? img[(y0 - 1) * 32 + tx] : neg1;
    float4 hprev = hmax3(r0, srcL, srcR, tx);
    float4 vcur = img[y0 * 32 + tx];
    float4 hcur = hmax3(vcur, srcL, srcR, tx);

    #pragma unroll 4
    for (int i = 0; i < 16; i++) {
        int y = y0 + i;
        float4 vn = (y + 1 < H_) ? img[(y + 1) * 32 + tx] : neg1;
        float4 hnext = hmax3(vn, srcL, srcR, tx);
        float mm[4];
        mm[0] = fmaxf(hprev.x, fmaxf(hcur.x, hnext.x));
        mm[1] = fmaxf(hprev.y, fmaxf(hcur.y, hnext.y));
        mm[2] = fmaxf(hprev.z, fmaxf(hcur.z, hnext.z));
        mm[3] = fmaxf(hprev.w, fmaxf(hcur.w, hnext.w));
        float vv[4] = {vcur.x, vcur.y, vcur.z, vcur.w};
        #pragma unroll
        for (int j = 0; j < 4; j++) emit(vv[j], mm[j], y, tx * 4 + j);
        hprev = hcur; hcur = hnext; vcur = vn;
    }
}

// 1024-bin suffix threshold (fallback): T = smallest bin with suffix >= 100
// (0 if total < 100); cntHi = count strictly above T.
__device__ __forceinline__ void find_suffix_thresh(const unsigned* __restrict__ h,
                                                   unsigned* __restrict__ seg,
                                                   unsigned* Tout,
                                                   unsigned* cntHiOut) {
    __syncthreads();
    int t = threadIdx.x;
    int base = t * 4;
    unsigned h0 = h[base], h1 = h[base + 1], h2 = h[base + 2], h3 = h[base + 3];
    seg[t] = h0 + h1 + h2 + h3;
    __syncthreads();
    for (int d = 1; d < 256; d <<= 1) {
        unsigned add = (t + d < 256) ? seg[t + d] : 0u;
        __syncthreads();
        seg[t] += add;
        __syncthreads();
    }
    unsigned mySuf = seg[t];
    unsigned nextSuf = (t < 255) ? seg[t + 1] : 0u;
    if (t == 0 && mySuf < 100u) { *Tout = 0u; *cntHiOut = mySuf - h0; }
    if (mySuf >= 100u && nextSuf < 100u) {
        unsigned cum = nextSuf;
        unsigned hv[4] = {h0, h1, h2, h3};
        for (int i = 3; i >= 0; i--) {
            cum += hv[i];
            if (cum >= 100u) { *Tout = (unsigned)(base + i); *cntHiOut = cum - hv[i]; break; }
        }
    }
    __syncthreads();
}

// ---------------------------------------------------------------------------
// K1: eager NMS scan, 2-phase register pipeline for load MLP. One block per
// (b,c) channel; thread = 16 rows x 4 cols. Candidates (local max AND bits >=
// F1) written DIRECTLY to the per-channel segment buf[bc*CHCAP] (LDS atomic
// for position only); raw count to chCnt[bc] unconditionally.
// grid: B_*C_ = 1280 blocks of 256.
// ---------------------------------------------------------------------------
__global__ __launch_bounds__(256) void nms_eager(const float* __restrict__ hm,
                                                 unsigned* __restrict__ chCnt,
                                                 unsigned long long* __restrict__ buf) {
    __shared__ unsigned lcnt;
    if (threadIdx.x == 0) lcnt = 0u;
    __syncthreads();

    int bc = blockIdx.x;         // b*C_ + c
    int c  = bc % C_;
    int tx = threadIdx.x & 31;
    int ty = threadIdx.x >> 5;
    int y0 = ty << 4;
    int lane = threadIdx.x & 63;
    int srcL = (lane > 0) ? lane - 1 : 0;
    int srcR = (lane < 63) ? lane + 1 : 63;
    const float4* img = (const float4*)(hm + (size_t)bc * HW_);
    const float4 neg1 = make_float4(-1.f, -1.f, -1.f, -1.f);
    unsigned long long* myseg = buf + (size_t)bc * CHCAP;

    auto emit4 = [&](float4 v, float4 m, int y) {
        float vv[4] = {v.x, v.y, v.z, v.w};
        float mm[4] = {m.x, m.y, m.z, m.w};
        #pragma unroll
        for (int j = 0; j < 4; j++) {
            float f = vv[j];
            if (f >= mm[j] && __float_as_uint(f) >= F1_BITS) {
                unsigned pos = atomicAdd(&lcnt, 1u);
                if (pos < CHCAP)
                    myseg[pos] = make_key(__float_as_uint(f), c, y, tx * 4 + j);
            }
        }
    };
    auto vmax3 = [](float4 a, float4 b, float4 cc) {
        float4 r;
        r.x = fmaxf(a.x, fmaxf(b.x, cc.x));
        r.y = fmaxf(a.y, fmaxf(b.y, cc.y));
        r.z = fmaxf(a.z, fmaxf(b.z, cc.z));
        r.w = fmaxf(a.w, fmaxf(b.w, cc.w));
        return r;
    };

    // phase 1: rows y0-1 .. y0+8 (R[k] = row y0-1+k) — 10 loads in flight
    float4 R[10], Hh[10];
    R[0] = (y0 > 0) ? img[(y0 - 1) * 32 + tx] : neg1;
    #pragma unroll
    for (int k = 1; k < 10; k++) R[k] = img[(y0 - 1 + k) * 32 + tx];
    #pragma unroll
    for (int k = 0; k < 10; k++) Hh[k] = hmax3(R[k], srcL, srcR, tx);
    #pragma unroll
    for (int k = 0; k < 8; k++)
        emit4(R[k + 1], vmax3(Hh[k], Hh[k + 1], Hh[k + 2]), y0 + k);

    // phase 2: rows y0+9 .. y0+16 (R2[j] = row y0+9+j) — 8 loads in flight
    float4 R2[8];
    #pragma unroll
    for (int j = 0; j < 7; j++) R2[j] = img[(y0 + 9 + j) * 32 + tx];
    R2[7] = (y0 + 16 < H_) ? img[(y0 + 16) * 32 + tx] : neg1;

    float4 hprev = Hh[8], hcur = Hh[9], vcur = R[9];
    #pragma unroll
    for (int j = 0; j < 8; j++) {
        float4 hn = hmax3(R2[j], srcL, srcR, tx);
        emit4(vcur, vmax3(hprev, hcur, hn), y0 + 8 + j);
        hprev = hcur; hcur = hn; vcur = R2[j];
    }

    __syncthreads();
    if (threadIdx.x == 0) chCnt[bc] = lcnt;
}

// ---------------------------------------------------------------------------
// K2: per-batch top-100. Fast path: ONE global pass over the 5120 padded
// slots builds a 384-fine-bin hist of (bits-F1)>>5 AND stashes all keys into
// LDS; suffix scan -> cut U2 + exact takeCnt; compact from the LDS stash.
// Guards (channel overflow / <100 total / stash overflow / takeCnt > SORTN)
// -> exact in-block 3-pass re-scan. Adaptive bitonic sort + decode + write.
// grid: B_ blocks of 256.
// ---------------------------------------------------------------------------
__global__ __launch_bounds__(256) void topk_decode(const float* __restrict__ hm,
                                                   const unsigned long long* __restrict__ buf,
                                                   const unsigned* __restrict__ chCnt,
                                                   const float* __restrict__ offset,
                                                   const float* __restrict__ wh,
                                                   float* __restrict__ out) {
    int b = blockIdx.x;
    int t = threadIdx.x;
    int lane = t & 63;
    __shared__ unsigned long long ls[LSCAP];  // 16 KB stash
    __shared__ unsigned long long s[SORTN];   // 8 KB sort buffer
    __shared__ unsigned lh[NBINS];            // fast: [0..FBINS); fb: all 1024
    __shared__ unsigned seg[256];
    __shared__ unsigned shC[256];
    __shared__ unsigned sufC[256];
    __shared__ unsigned scnt[C_];
    __shared__ unsigned rawTotS, ovfS, stashCnt, U2s, takeS, T1s, cntHiS, Us, cntL;

    if (t == 0) { rawTotS = 0u; ovfS = 0u; stashCnt = 0u; cntL = 0u;
                  U2s = 0u; takeS = 0u; T1s = 0u; cntHiS = 0u; Us = 0u; }
    lh[t] = 0u; lh[t + 256] = 0u;             // fast path uses FBINS=512
    __syncthreads();
    if (t < C_) {
        unsigned r = chCnt[b * C_ + t];
        atomicAdd(&rawTotS, r);
        if (r > CHCAP) atomicOr(&ovfS, 1u);
        scnt[t] = r > CHCAP ? CHCAP : r;
    }
    __syncthreads();
    bool fb = (rawTotS < 100u) || (ovfS != 0u);

    const unsigned long long* bufb = buf + (size_t)b * C_ * CHCAP;
    unsigned n2 = 0u;

    if (!fb) {
        // single global pass: fine hist + LDS stash
        #pragma unroll 4
        for (unsigned i0 = 0; i0 < (unsigned)PADTOT; i0 += 256) {
            unsigned i  = i0 + t;
            unsigned sg = i >> 6;              // CHCAP == 64
            unsigned off = i & (CHCAP - 1u);
            bool valid = off < scnt[sg];
            unsigned long long key = 0ull;
            if (valid) {
                key = bufb[i];
                unsigned bin = ((unsigned)(key >> 32) - F1_BITS) >> FSHIFT;
                if (bin > FBINS - 1u) bin = FBINS - 1u;
                atomicAdd(&lh[bin], 1u);
            }
            unsigned long long m = __ballot(valid);
            if (m != 0ull) {
                int leader = __ffsll((unsigned long long)m) - 1;
                unsigned wcnt = (unsigned)__popcll(m);
                unsigned wbase = 0u;
                if (lane == leader) wbase = atomicAdd(&stashCnt, wcnt);
                wbase = __shfl(wbase, leader);
                if (valid) {
                    unsigned pos = wbase + (unsigned)__popcll(m & ((1ull << lane) - 1ull));
                    if (pos < LSCAP) ls[pos] = key;
                }
            }
        }
        __syncthreads();
        if (stashCnt > LSCAP) fb = true;
        // suffix scan over FBINS (2 bins/thread) -> U2, exact takeCnt
        unsigned g0 = lh[t * 2], g1 = lh[t * 2 + 1];
        seg[t] = g0 + g1;
        __syncthreads();
        for (int d = 1; d < 256; d <<= 1) {
            unsigned add = (t + d < 256) ? seg[t + d] : 0u;
            __syncthreads();
            seg[t] += add;
            __syncthreads();
        }
        unsigned mySuf = seg[t];
        unsigned nextSuf = (t < 255) ? seg[t + 1] : 0u;
        if (mySuf >= 100u && nextSuf < 100u) {   // exists since rawTot >= 100
            unsigned cum1 = nextSuf + g1;
            if (cum1 >= 100u) { U2s = (unsigned)(t * 2 + 1); takeS = cum1; }
            else              { U2s = (unsigned)(t * 2);     takeS = cum1 + g0; }
        }
        __syncthreads();
        unsigned U2 = U2s, takeCnt = takeS;
        if (takeCnt > SORTN) fb = true;          // massive tie block
        if (!fb) {
            // compact from LDS stash (keys with fine-bin >= U2)
            unsigned sn = stashCnt;
            for (unsigned i0 = 0; i0 < sn; i0 += 256) {
                unsigned i = i0 + t;
                bool valid = (i < sn);
                unsigned long long key = valid ? ls[i] : 0ull;
                bool take = false;
                if (valid) {
                    unsigned bin = ((unsigned)(key >> 32) - F1_BITS) >> FSHIFT;
                    if (bin > FBINS - 1u) bin = FBINS - 1u;
                    take = (bin >= U2);
                }
                unsigned long long m = __ballot(take);
                if (m != 0ull) {
                    int leader = __ffsll((unsigned long long)m) - 1;
                    unsigned wcnt = (unsigned)__popcll(m);
                    unsigned wbase = 0u;
                    if (lane == leader) wbase = atomicAdd(&cntL, wcnt);
                    wbase = __shfl(wbase, leader);
                    if (take) {
                        unsigned pos = wbase + (unsigned)__popcll(m & ((1ull << lane) - 1ull));
                        s[pos] = key;
                    }
                }
            }
            __syncthreads();
            n2 = cntL;
        }
    }

    if (fb) {
        // ---- exact fallback: in-block 3-pass re-scan of this batch's channels
        __syncthreads();
        for (int i = t; i < NBINS; i += 256) lh[i] = 0u;
        shC[t] = 0u;
        if (t == 0) { cntL = 0u; T1s = 0u; cntHiS = 0u; Us = 0u; }
        __syncthreads();

        // pass 1: 1024-bin hist over all local maxima with f > 0.01
        for (int cc = 0; cc < C_; cc++) {
            const float4* im = (const float4*)(hm + ((size_t)b * C_ + cc) * HW_);
            nms_scan_channel(im, [&](float f, float m, int y, int x) {
                bool hit = (f > 0.01f && f >= m);
                unsigned bin = 0u;
                if (hit) {
                    bin = (__float_as_uint(f) >> 16) - BIN_BASE;
                    if (bin > NBINS - 1) bin = NBINS - 1;
                }
                hist_add(lh, hit, bin, lane);
            });
        }
        find_suffix_thresh(lh, seg, &T1s, &cntHiS);
        unsigned T1 = T1s, cntHi = cntHiS;

        // pass 2: collect bin>T1 keys; sub-hist bits[15:8] for bin==T1
        for (int cc = 0; cc < C_; cc++) {
            const float4* im = (const float4*)(hm + ((size_t)b * C_ + cc) * HW_);
            nms_scan_channel(im, [&](float f, float m, int y, int x) {
                if (f > 0.01f && f >= m) {
                    unsigned bits = __float_as_uint(f);
                    unsigned bin = (bits >> 16) - BIN_BASE;
                    if (bin > NBINS - 1) bin = NBINS - 1;
                    if (bin > T1) {
                        unsigned pos = atomicAdd(&cntL, 1u);
                        if (pos < SORTN) s[pos] = make_key(bits, cc, y, x);
                    } else if (bin == T1) {
                        atomicAdd(&shC[(bits >> 8) & 255u], 1u);
                    }
                }
            });
        }
        __syncthreads();
        sufC[t] = shC[t];
        __syncthreads();
        for (int d = 1; d < 256; d <<= 1) {
            unsigned add = (t + d < 256) ? sufC[t + d] : 0u;
            __syncthreads();
            sufC[t] += add;
            __syncthreads();
        }
        unsigned myS = cntHi + sufC[t];
        unsigned nxS = cntHi + ((t < 255) ? sufC[t + 1] : 0u);
        if (t == 0 && myS < 100u) Us = 0u;
        if (myS >= 100u && nxS < 100u) Us = (unsigned)t;
        __syncthreads();
        unsigned U = Us;

        // pass 3: collect bin==T1 && sub>=U keys
        for (int cc = 0; cc < C_; cc++) {
            const float4* im = (const float4*)(hm + ((size_t)b * C_ + cc) * HW_);
            nms_scan_channel(im, [&](float f, float m, int y, int x) {
                if (f > 0.01f && f >= m) {
                    unsigned bits = __float_as_uint(f);
                    unsigned bin = (bits >> 16) - BIN_BASE;
                    if (bin > NBINS - 1) bin = NBINS - 1;
                    if (bin == T1 && ((bits >> 8) & 255u) >= U) {
                        unsigned pos = atomicAdd(&cntL, 1u);
                        if (pos < SORTN) s[pos] = make_key(bits, cc, y, x);
                    }
                }
            });
        }
        __syncthreads();
        n2 = cntL;
    }
    if (n2 > SORTN) n2 = SORTN;

    // adaptive bitonic sort descending (0 pads sink to the bottom)
    unsigned SN = (n2 <= 256u) ? 256u : SORTN;
    for (unsigned i = n2 + t; i < SN; i += 256) s[i] = 0ull;
    __syncthreads();
    for (unsigned k = 2; k <= SN; k <<= 1) {
        for (unsigned j = k >> 1; j > 0; j >>= 1) {
            for (unsigned tt = t; tt < SN; tt += 256) {
                unsigned ixj = tt ^ j;
                if (ixj > tt) {
                    unsigned long long a = s[tt], bb = s[ixj];
                    bool desc = ((tt & k) == 0u);
                    if (desc ? (a < bb) : (a > bb)) { s[tt] = bb; s[ixj] = a; }
                }
            }
            __syncthreads();
        }
    }

    // decode + write
    int r = t;
    if (r < 100) {
        float idv, sc, b0, b1, b2, b3;
        if ((unsigned)r < n2) {
            unsigned long long key = s[r];
            unsigned bits = (unsigned)(key >> 32);
            unsigned idx  = 0xFFFFFFFFu - (unsigned)(key & 0xFFFFFFFFu);
            float v = __uint_as_float(bits);
            int cc = (int)(idx >> 14);
            int sp = (int)(idx & 16383u);
            int y  = sp >> 7;
            int x  = sp & 127;
            const float* offb = offset + (size_t)b * 2 * HW_;
            const float* whb  = wh + (size_t)b * 2 * HW_;
            float ox = offb[sp], oy = offb[HW_ + sp];
            float wwv = whb[sp], hh = whb[HW_ + sp];
            float cx = (float)x + ox;
            float cy = (float)y + oy;
            idv = (float)cc;
            sc  = v;
            b0 = (cx - wwv * 0.5f) * 4.0f;
            b1 = (cy - hh * 0.5f) * 4.0f;
            b2 = (cx + wwv * 0.5f) * 4.0f;
            b3 = (cy + hh * 0.5f) * 4.0f;
        } else {
            idv = -1.0f; sc = -1.0f;
            b0 = b1 = b2 = b3 = -4.0f;   // where(keep, bbox, -1) * SCALE
        }
        int o = b * 100 + r;
        out[o]        = idv;
        out[1600 + o] = sc;
        float* bb = out + 3200 + o * 4;
        bb[0] = b0; bb[1] = b1; bb[2] = b2; bb[3] = b3;
    }
}

// ---------------------------------------------------------------------------
extern "C" void kernel_launch(void* const* d_in, const int* in_sizes, int n_in,
                              void* d_out, int out_size, void* d_ws, size_t ws_size,
                              hipStream_t stream) {
    const float* heatmap = (const float*)d_in[0];
    const float* offset  = (const float*)d_in[1];
    const float* wh      = (const float*)d_in[2];
    float* out = (float*)d_out;

    char* ws = (char*)d_ws;
    unsigned* chCnt = (unsigned*)(ws + WS_CC_OFF);
    unsigned long long* buf = (unsigned long long*)(ws + WS_BUF_OFF);

    nms_eager<<<dim3(B_ * C_), dim3(256), 0, stream>>>(heatmap, chCnt, buf);
    topk_decode<<<dim3(B_), dim3(256), 0, stream>>>(heatmap, buf, chCnt,
                                                    offset, wh, out);
}